// Round 4
// baseline (310.731 us; speedup 1.0000x reference)
//
#include <hip/hip_runtime.h>
#include <cstdint>

typedef float f32x4  __attribute__((ext_vector_type(4)));
typedef float f32x16 __attribute__((ext_vector_type(16)));
typedef short bf16x8 __attribute__((ext_vector_type(8)));
typedef unsigned int u32;

#define QP_BASE 0
#define KP_BASE 16384
#define VT_BASE 32768

__device__ __forceinline__ unsigned short f2bf(float f){
  union { float f; uint32_t u; } v; v.f = f;
  uint32_t u = v.u;
  return (unsigned short)((u + 0x7FFFu + ((u >> 16) & 1u)) >> 16);  // RNE
}
__device__ __forceinline__ float bf2f(unsigned short h){
  union { uint32_t u; float f; } v; v.u = ((uint32_t)h) << 16;
  return v.f;
}
__device__ __forceinline__ u32 pack2bf(float a, float b){
  return (u32)f2bf(a) | ((u32)f2bf(b) << 16);
}
__device__ __forceinline__ f32x4 mfma16(bf16x8 a, bf16x8 b, f32x4 c){
  return __builtin_amdgcn_mfma_f32_16x16x32_bf16(a, b, c, 0, 0, 0);
}
__device__ __forceinline__ f32x16 mfma32(bf16x8 a, bf16x8 b, f32x16 c){
  return __builtin_amdgcn_mfma_f32_32x32x16_bf16(a, b, c, 0, 0, 0);
}
__device__ __forceinline__ void gload_lds16(const void* gsrc, void* ldst){
  __builtin_amdgcn_global_load_lds(
    (const __attribute__((address_space(1))) unsigned int*)gsrc,
    (__attribute__((address_space(3))) unsigned int*)ldst, 16, 0, 0);
}

// ---------------- prep ----------------
// wsu layout (shorts): WT_q [0,16384) | WT_v [16384,32768) | WT_k [32768,65536)
//   WT_oh [65536,81920) | WT_ol [81920,98304) | bias_t u32[16384] at short 98304
__global__ void prep_kernel(const float* __restrict__ wq, const float* __restrict__ wk,
                            const float* __restrict__ wv, const float* __restrict__ wo,
                            const float* __restrict__ btab, unsigned short* __restrict__ wsu)
{
  const int idx = blockIdx.x * 256 + threadIdx.x;
  if (idx < 16384){                          // WT_q[n][k] = wq[k][n], k-swizzled
    const int n = idx >> 7, k = idx & 127;
    wsu[n*128 + (k ^ ((n & 7) << 3))] = f2bf(wq[k*128 + n]);
  } else if (idx < 32768){                   // WT_v
    const int i = idx - 16384, n = i >> 7, k = i & 127;
    wsu[16384 + n*128 + (k ^ ((n & 7) << 3))] = f2bf(wv[k*128 + n]);
  } else if (idx < 65536){                   // WT_k (K=256)
    const int i = idx - 32768, n = i >> 8, k = i & 255;
    wsu[32768 + n*256 + (k ^ ((n & 7) << 3))] = f2bf(wk[k*128 + n]);
  } else if (idx < 81920){                   // WT_o hi/lo (linear [n][k])
    const int i = idx - 65536, n = i >> 7, k = i & 127;
    const float f = wo[k*128 + n];
    const unsigned short hv = f2bf(f);
    wsu[65536 + n*128 + k] = hv;
    wsu[81920 + n*128 + k] = f2bf(f - bf2f(hv));
  } else if (idx < 98304){                   // bias_t (reg-layout bf16 pairs)
    const int i = idx - 81920;
    const int q  = i & 31;
    const int ib = (i >> 5) & 7;
    const int h5 = (i >> 8) & 1;
    const int t  = (i >> 9) & 1;
    const int qh = (i >> 10) & 1;
    const int h  = (i >> 11);
    const int qg = qh*32 + q;
    const int qi = qg >> 3, qj = qg & 7;
    u32 wv2 = 0;
#pragma unroll
    for (int e = 0; e < 2; ++e){
      const int r = 2*ib + e;
      const int key = t*32 + 4*h5 + (r & 3) + 8*(r >> 2);
      const int ki = key >> 3, kj = key & 7;
      const int rel = (qi - ki + 7) * 15 + (qj - kj + 7);
      wv2 |= ((u32)f2bf(btab[rel*8 + h])) << (16*e);
    }
    reinterpret_cast<u32*>(wsu + 98304)[i] = wv2;
  }
}

// =================== projection kernels (barrier-free window loop) ===========
// MODE 0 (q/k): outstage per-wave region -> coalesced copy to outg row-chunks:
//   byte = (row<<8) + ((ch*2) ^ ((row&15)<<4))
// MODE 1 (v): register transpose -> direct 16B stores to vt chunks:
//   byte = (h<<11) + (c16<<7) + ((key*2) ^ ((c16&7)<<4))
template<int KC, int MODE>
__device__ __forceinline__ void proj_body(const float* __restrict__ X,
    const float* __restrict__ bias, const unsigned short* __restrict__ wbase_g,
    unsigned short* __restrict__ outg, char* smem, int w0, int nwin)
{
  constexpr int NKS = KC / 32;
  constexpr int SH  = (KC == 128) ? 8 : 9;
  constexpr int WBYTES = KC * 128 * 2;
  const int tid = threadIdx.x;
  const int wave = tid >> 6, lane = tid & 63;
  const int g = lane >> 4, c16 = lane & 15;

  // stage weights once
#pragma unroll
  for (int i = 0; i < WBYTES/4096; ++i)
    gload_lds16(reinterpret_cast<const char*>(wbase_g) + i*4096 + tid*16, smem + i*4096 + tid*16);
  __syncthreads();
  char* outstage = smem + WBYTES;

  float bias_r[8];
#pragma unroll
  for (int ct = 0; ct < 8; ++ct) bias_r[ct] = bias[ct*16 + c16];

  const int rA = 16*wave + c16;
  const int rowoff = ((rA >> 3) << 8) + (rA & 7);   // token offset within window grid

  float4 raw[2*NKS];
  {
    const int win = w0;
    const long winbase = (long)(win >> 10)*65536 + (long)((win >> 5) & 31)*2048 + (win & 31)*8;
    const float* xrow = X + (winbase + rowoff) * KC;
#pragma unroll
    for (int ks = 0; ks < NKS; ++ks){
      const float4* p = reinterpret_cast<const float4*>(xrow + 32*ks + 8*g);
      raw[2*ks] = p[0]; raw[2*ks+1] = p[1];
    }
  }

  for (int wl = 0; wl < nwin; ++wl){
    const int win = w0 + wl;
    // convert current A
    bf16x8 a[NKS];
#pragma unroll
    for (int ks = 0; ks < NKS; ++ks){
      const float4 x0 = raw[2*ks], x1 = raw[2*ks+1];
      bf16x8 t;
      t[0]=(short)f2bf(x0.x); t[1]=(short)f2bf(x0.y); t[2]=(short)f2bf(x0.z); t[3]=(short)f2bf(x0.w);
      t[4]=(short)f2bf(x1.x); t[5]=(short)f2bf(x1.y); t[6]=(short)f2bf(x1.z); t[7]=(short)f2bf(x1.w);
      a[ks] = t;
    }
    // prefetch next window's A
    if (wl + 1 < nwin){
      const int win2 = win + 1;
      const long wb2 = (long)(win2 >> 10)*65536 + (long)((win2 >> 5) & 31)*2048 + (win2 & 31)*8;
      const float* xrow2 = X + (wb2 + rowoff) * KC;
#pragma unroll
      for (int ks = 0; ks < NKS; ++ks){
        const float4* p = reinterpret_cast<const float4*>(xrow2 + 32*ks + 8*g);
        raw[2*ks] = p[0]; raw[2*ks+1] = p[1];
      }
    }
    // MFMA
    f32x4 acc[8];
#pragma unroll
    for (int ct = 0; ct < 8; ++ct) acc[ct] = f32x4{0.f,0.f,0.f,0.f};
#pragma unroll
    for (int ct = 0; ct < 8; ++ct){
      const int n = ct*16 + c16;
#pragma unroll
      for (int ks = 0; ks < NKS; ++ks){
        const bf16x8 b = *reinterpret_cast<const bf16x8*>(
            smem + ((n << SH) + (((32*ks + 8*g) << 1) ^ ((n & 7) << 4))));
        acc[ct] = mfma16(a[ks], b, acc[ct]);
      }
    }

    if (MODE == 0){
      // per-wave outstage region [wave*4096, +4096)
#pragma unroll
      for (int ct = 0; ct < 8; ++ct){
#pragma unroll
        for (int r = 0; r < 4; ++r){
          const int row = 16*wave + 4*g + r;
          const int off = (row << 8) + (((ct*16 + c16) << 1) ^ ((row & 15) << 4));
          *reinterpret_cast<unsigned short*>(outstage + off) = f2bf(acc[ct][r] + bias_r[ct]);
        }
      }
      asm volatile("s_waitcnt lgkmcnt(0)" ::: "memory");
      char* dst = reinterpret_cast<char*>(outg) + (size_t)win * 16384 + wave*4096;
      const char* srcs = outstage + wave*4096;
#pragma unroll
      for (int i = 0; i < 4; ++i){
        const uint4 d = *reinterpret_cast<const uint4*>(srcs + i*1024 + lane*16);
        *reinterpret_cast<uint4*>(dst + i*1024 + lane*16) = d;
      }
    } else {
      // v: pack + shfl_xor(16) pair-merge -> direct 16B stores, no LDS, no barrier
      u32 pa[8], pb[8];
#pragma unroll
      for (int ct = 0; ct < 8; ++ct){
        const float v0 = acc[ct][0] + bias_r[ct], v1 = acc[ct][1] + bias_r[ct];
        const float v2 = acc[ct][2] + bias_r[ct], v3 = acc[ct][3] + bias_r[ct];
        pa[ct] = pack2bf(v0, v1); pb[ct] = pack2bf(v2, v3);
      }
      const int p  = g & 1;            // ct-half this lane stores
      const int kk = g >> 1;
      const int t  = 2*wave + kk;      // 8-key chunk index
      u32 sa[4], sb[4];
#pragma unroll
      for (int i = 0; i < 4; ++i){
        const int cs = p ? i : 4 + i;  // ct I send (partner's stored half)
        sa[i] = (u32)__shfl_xor((int)pa[cs], 16);
        sb[i] = (u32)__shfl_xor((int)pb[cs], 16);
      }
      char* wout = reinterpret_cast<char*>(outg) + (size_t)win * 16384;
#pragma unroll
      for (int i = 0; i < 4; ++i){
        const int ct2 = 4*p + i;
        uint4 chunk;
        if (p == 0){ chunk.x = pa[ct2]; chunk.y = pb[ct2]; chunk.z = sa[i]; chunk.w = sb[i]; }
        else       { chunk.x = sa[i];   chunk.y = sb[i];   chunk.z = pa[ct2]; chunk.w = pb[ct2]; }
        *reinterpret_cast<uint4*>(wout + ct2*2048 + c16*128 + 16*(t ^ (c16 & 7))) = chunk;
      }
    }
  }
}

__global__ __launch_bounds__(256, 3) void proj_q(const float* __restrict__ qq,
    const float* __restrict__ b_q, const unsigned short* __restrict__ wsu,
    unsigned short* __restrict__ qs)
{
  __shared__ char smem[49152];   // 32K weights + 16K outstage
  proj_body<128,0>(qq, b_q, wsu, qs, smem, blockIdx.x*4, 4);
}
__global__ __launch_bounds__(256, 3) void proj_v(const float* __restrict__ vv,
    const float* __restrict__ b_v, const unsigned short* __restrict__ wsu,
    unsigned short* __restrict__ vsg)
{
  __shared__ char smem[32768];   // 32K weights only
  proj_body<128,1>(vv, b_v, wsu + 16384, vsg, smem, blockIdx.x*4, 4);
}
__global__ __launch_bounds__(256, 2) void proj_k(const float* __restrict__ kkin,
    const float* __restrict__ b_k, const unsigned short* __restrict__ wsu,
    unsigned short* __restrict__ ksg)
{
  __shared__ char smem[81920];   // 64K weights + 16K outstage
  proj_body<256,0>(kkin, b_k, wsu + 32768, ksg, smem, blockIdx.x*8, 8);
}

// =================== attention + o-projection, 512 threads / window ===========
__global__ __launch_bounds__(512, 4) void attn_kernel(
    const unsigned short* __restrict__ qs, const unsigned short* __restrict__ ksg,
    const unsigned short* __restrict__ vsg, const unsigned short* __restrict__ wsu,
    const float* __restrict__ b_o, float* __restrict__ out)
{
  __shared__ char smem[49152];   // q 16K | k 16K | vt 16K ; after: yh [0,16K), yl [16K,32K)
  const int tid = threadIdx.x;
  const int wave = tid >> 6, lane = tid & 63;
  const int l31 = lane & 31, h5 = lane >> 5;
  const int qh = wave & 1, hp = wave >> 1;

  const int win = blockIdx.x;
  const int bb = win >> 10, wy = (win >> 5) & 31, wx = win & 31;
  const long winbase = (long)bb * 65536 + (long)wy * 2048 + wx * 8;

  const u32* bias_u = reinterpret_cast<const u32*>(wsu + 98304);

  {
    const char* srcs[3] = {
      reinterpret_cast<const char*>(qs)  + (size_t)win * 16384,
      reinterpret_cast<const char*>(ksg) + (size_t)win * 16384,
      reinterpret_cast<const char*>(vsg) + (size_t)win * 16384 };
#pragma unroll
    for (int rg = 0; rg < 3; ++rg)
#pragma unroll
      for (int j = 0; j < 2; ++j){
        const int off = j*8192 + tid*16;
        gload_lds16(srcs[rg] + off, smem + rg*16384 + off);
      }
  }
  __syncthreads();

  f32x16 y[2];
#pragma unroll
  for (int hh = 0; hh < 2; ++hh){
    const int h = 2*hp + hh;
    const int chb = (h*16 + 8*h5) * 2;
    bf16x8 kf0, kf1, qf;
    { const int row = l31;
      kf0 = *reinterpret_cast<const bf16x8*>(smem + KP_BASE + (row<<8) + (chb ^ ((row&15)<<4))); }
    { const int row = 32 + l31;
      kf1 = *reinterpret_cast<const bf16x8*>(smem + KP_BASE + (row<<8) + (chb ^ ((row&15)<<4))); }
    { const int row = qh*32 + l31;
      qf  = *reinterpret_cast<const bf16x8*>(smem + QP_BASE + (row<<8) + (chb ^ ((row&15)<<4))); }
    f32x16 z = {};
    f32x16 s0 = mfma32(kf0, qf, z);
    f32x16 s1 = mfma32(kf1, qf, z);

    const u32* bb2 = bias_u + ((((h*2 + qh)*2 + 0)*2 + h5)*8)*32 + l31;
    float t[32];
#pragma unroll
    for (int i = 0; i < 8; ++i){
      const u32 w0 = bb2[i*32];
      const u32 w1 = bb2[512 + i*32];
      t[2*i]     = fmaf(s0[2*i],   0.25f, bf2f((unsigned short)(w0 & 0xffff)));
      t[2*i+1]   = fmaf(s0[2*i+1], 0.25f, bf2f((unsigned short)(w0 >> 16)));
      t[16+2*i]  = fmaf(s1[2*i],   0.25f, bf2f((unsigned short)(w1 & 0xffff)));
      t[17+2*i]  = fmaf(s1[2*i+1], 0.25f, bf2f((unsigned short)(w1 >> 16)));
    }
    float m = t[0];
#pragma unroll
    for (int r = 1; r < 32; ++r) m = fmaxf(m, t[r]);
    m = fmaxf(m, __shfl_xor(m, 32));
    float sum = 0.f;
#pragma unroll
    for (int r = 0; r < 32; ++r){ t[r] = __expf(t[r] - m); sum += t[r]; }
    sum += __shfl_xor(sum, 32);
    const float rs = 1.0f / sum;
    u32 pk0[8], pk1[8];
#pragma unroll
    for (int i = 0; i < 8; ++i){
      pk0[i] = pack2bf(t[2*i]*rs,    t[2*i+1]*rs);
      pk1[i] = pack2bf(t[16+2*i]*rs, t[17+2*i]*rs);
    }

    f32x16 yy = {};
    const int chr = l31 & 15;
#pragma unroll
    for (int m4 = 0; m4 < 4; ++m4){
      const int jb = 4*(m4 & 1);
      const u32 a0 = (m4 < 2) ? pk0[jb]   : pk1[jb];
      const u32 a1 = (m4 < 2) ? pk0[jb+1] : pk1[jb+1];
      const u32 a2 = (m4 < 2) ? pk0[jb+2] : pk1[jb+2];
      const u32 a3 = (m4 < 2) ? pk0[jb+3] : pk1[jb+3];
      const u32 s0w = (u32)__shfl_xor((int)a0, 32);
      const u32 s1w = (u32)__shfl_xor((int)a1, 32);
      const u32 s2w = (u32)__shfl_xor((int)a2, 32);
      const u32 s3w = (u32)__shfl_xor((int)a3, 32);
      union { u32 w[4]; bf16x8 v; } afu;
      afu.w[0] = h5 ? s2w : a0;
      afu.w[1] = h5 ? s3w : a1;
      afu.w[2] = h5 ? a2  : s0w;
      afu.w[3] = h5 ? a3  : s1w;
      const int kb = 32*m4 + 16*h5;
      const bf16x8 bv = *reinterpret_cast<const bf16x8*>(
          smem + VT_BASE + (h<<11) + (chr<<7) + (kb ^ ((chr & 7) << 4)));
      yy = mfma32(afu.v, bv, yy);
    }
    y[hh] = yy;
  }
  __syncthreads();

  if (l31 < 16){
#pragma unroll
    for (int hh = 0; hh < 2; ++hh){
      const int ch = (2*hp + hh)*16 + l31;
#pragma unroll
      for (int r = 0; r < 16; ++r){
        const int row = qh*32 + (r & 3) + 8*(r >> 2) + 4*h5;
        const float v = y[hh][r];
        const unsigned short hv = f2bf(v);
        const unsigned short lv = f2bf(v - bf2f(hv));
        const int byte = (row << 8) + ((ch << 1) ^ ((row & 15) << 4));
        *reinterpret_cast<unsigned short*>(smem + byte)         = hv;
        *reinterpret_cast<unsigned short*>(smem + 16384 + byte) = lv;
      }
    }
  }
  __syncthreads();

  {
    const int g = lane >> 4, c16 = lane & 15;
    const int ct = wave;
    const unsigned short* WT_oh = wsu + 65536;
    const unsigned short* WT_ol = wsu + 81920;
    bf16x8 bh[4], bl[4];
#pragma unroll
    for (int ks = 0; ks < 4; ++ks){
      bh[ks] = *reinterpret_cast<const bf16x8*>(WT_oh + (ct*16+c16)*128 + 32*ks + 8*g);
      bl[ks] = *reinterpret_cast<const bf16x8*>(WT_ol + (ct*16+c16)*128 + 32*ks + 8*g);
    }
    const float bov = b_o[ct*16 + c16];
#pragma unroll
    for (int rt = 0; rt < 4; ++rt){
      const int row2 = rt*16 + c16;
      bf16x8 ah[4], al[4];
#pragma unroll
      for (int ks = 0; ks < 4; ++ks){
        const int byte = (row2 << 8) + ((64*ks + 16*g) ^ ((row2 & 15) << 4));
        ah[ks] = *reinterpret_cast<const bf16x8*>(smem + byte);
        al[ks] = *reinterpret_cast<const bf16x8*>(smem + 16384 + byte);
      }
      f32x4 acc = {};
#pragma unroll
      for (int ks = 0; ks < 4; ++ks){
        acc = mfma16(ah[ks], bh[ks], acc);
        acc = mfma16(al[ks], bh[ks], acc);
        acc = mfma16(ah[ks], bl[ks], acc);
      }
#pragma unroll
      for (int r = 0; r < 4; ++r){
        const int R = rt*16 + 4*g + r;
        const long tok = winbase + (long)(R >> 3)*256 + (R & 7);
        out[tok*128 + ct*16 + c16] = acc[r] + bov;
      }
    }
  }
}

extern "C" void kernel_launch(void* const* d_in, const int* in_sizes, int n_in,
                              void* d_out, int out_size, void* d_ws, size_t ws_size,
                              hipStream_t stream)
{
  (void)in_sizes; (void)n_in; (void)out_size; (void)ws_size;
  const float* qq   = (const float*)d_in[0];
  const float* kk   = (const float*)d_in[1];
  const float* vv   = (const float*)d_in[2];
  const float* w_q  = (const float*)d_in[3];
  const float* b_q  = (const float*)d_in[4];
  const float* w_k  = (const float*)d_in[5];
  const float* b_k  = (const float*)d_in[6];
  const float* w_v  = (const float*)d_in[7];
  const float* b_v  = (const float*)d_in[8];
  const float* w_o  = (const float*)d_in[9];
  const float* b_o  = (const float*)d_in[10];
  const float* btab = (const float*)d_in[11];
  unsigned short* wsu = (unsigned short*)d_ws;
  float* out = (float*)d_out;

  unsigned short* qsp = wsu + 131072;            // byte 262144
  unsigned short* ksp = qsp + 33554432;          // +64MB
  unsigned short* vsp = ksp + 33554432;          // +64MB

  prep_kernel<<<384, 256, 0, stream>>>(w_q, w_k, w_v, w_o, btab, wsu);
  proj_q<<<1024, 256, 0, stream>>>(qq, b_q, wsu, qsp);
  proj_v<<<1024, 256, 0, stream>>>(vv, b_v, wsu, vsp);
  proj_k<<<512,  256, 0, stream>>>(kk, b_k, wsu, ksp);
  attn_kernel<<<4096, 512, 0, stream>>>(qsp, ksp, vsp, wsu, b_o, out);
}

// Round 5
// 274.232 us; speedup vs baseline: 1.1331x; 1.1331x over previous
//
#include <hip/hip_runtime.h>
#include <cstdint>

typedef float f32x4  __attribute__((ext_vector_type(4)));
typedef float f32x16 __attribute__((ext_vector_type(16)));
typedef short bf16x8 __attribute__((ext_vector_type(8)));
typedef unsigned int u32;

#define QP_BASE 0
#define KP_BASE 16384
#define VT_BASE 32768

__device__ __forceinline__ unsigned short f2bf(float f){
  union { float f; uint32_t u; } v; v.f = f;
  uint32_t u = v.u;
  return (unsigned short)((u + 0x7FFFu + ((u >> 16) & 1u)) >> 16);  // RNE
}
__device__ __forceinline__ float bf2f(unsigned short h){
  union { uint32_t u; float f; } v; v.u = ((uint32_t)h) << 16;
  return v.f;
}
__device__ __forceinline__ u32 pack2bf(float a, float b){
  return (u32)f2bf(a) | ((u32)f2bf(b) << 16);
}
__device__ __forceinline__ f32x4 mfma16(bf16x8 a, bf16x8 b, f32x4 c){
  return __builtin_amdgcn_mfma_f32_16x16x32_bf16(a, b, c, 0, 0, 0);
}
__device__ __forceinline__ f32x16 mfma32(bf16x8 a, bf16x8 b, f32x16 c){
  return __builtin_amdgcn_mfma_f32_32x32x16_bf16(a, b, c, 0, 0, 0);
}
__device__ __forceinline__ void gload_lds16(const void* gsrc, void* ldst){
  __builtin_amdgcn_global_load_lds(
    (const __attribute__((address_space(1))) unsigned int*)gsrc,
    (__attribute__((address_space(3))) unsigned int*)ldst, 16, 0, 0);
}

// ---------------- prep ----------------
// wsu layout (shorts): WT_q [0,16384) | WT_v [16384,32768) | WT_k [32768,65536)
//   WT_oh [65536,81920) | WT_ol [81920,98304) | bias_t u32[16384] at short 98304
__global__ void prep_kernel(const float* __restrict__ wq, const float* __restrict__ wk,
                            const float* __restrict__ wv, const float* __restrict__ wo,
                            const float* __restrict__ btab, unsigned short* __restrict__ wsu)
{
  const int idx = blockIdx.x * 256 + threadIdx.x;
  if (idx < 16384){                          // WT_q[n][k] = wq[k][n], k-swizzled
    const int n = idx >> 7, k = idx & 127;
    wsu[n*128 + (k ^ ((n & 7) << 3))] = f2bf(wq[k*128 + n]);
  } else if (idx < 32768){                   // WT_v
    const int i = idx - 16384, n = i >> 7, k = i & 127;
    wsu[16384 + n*128 + (k ^ ((n & 7) << 3))] = f2bf(wv[k*128 + n]);
  } else if (idx < 65536){                   // WT_k (K=256)
    const int i = idx - 32768, n = i >> 8, k = i & 255;
    wsu[32768 + n*256 + (k ^ ((n & 7) << 3))] = f2bf(wk[k*128 + n]);
  } else if (idx < 81920){                   // WT_o hi/lo (linear [n][k])
    const int i = idx - 65536, n = i >> 7, k = i & 127;
    const float f = wo[k*128 + n];
    const unsigned short hv = f2bf(f);
    wsu[65536 + n*128 + k] = hv;
    wsu[81920 + n*128 + k] = f2bf(f - bf2f(hv));
  } else if (idx < 98304){                   // bias_t (reg-layout bf16 pairs)
    const int i = idx - 81920;
    const int q  = i & 31;
    const int ib = (i >> 5) & 7;
    const int h5 = (i >> 8) & 1;
    const int t  = (i >> 9) & 1;
    const int qh = (i >> 10) & 1;
    const int h  = (i >> 11);
    const int qg = qh*32 + q;
    const int qi = qg >> 3, qj = qg & 7;
    u32 wv2 = 0;
#pragma unroll
    for (int e = 0; e < 2; ++e){
      const int r = 2*ib + e;
      const int key = t*32 + 4*h5 + (r & 3) + 8*(r >> 2);
      const int ki = key >> 3, kj = key & 7;
      const int rel = (qi - ki + 7) * 15 + (qj - kj + 7);
      wv2 |= ((u32)f2bf(btab[rel*8 + h])) << (16*e);
    }
    reinterpret_cast<u32*>(wsu + 98304)[i] = wv2;
  }
}

// =================== projection kernels ===========
// MODE 0 (q/k): per-wave outstage -> coalesced copy. chunk byte = (row<<8) + ((ch*2)^((row&15)<<4))
// MODE 2 (v):  u16 scatter to block outstage in vt layout -> barrier -> coalesced copy.
//              vt byte = (ct<<11) + (c16<<7) + ((key*2)^((c16&7)<<4))
template<int KC, int MODE>
__device__ __forceinline__ void proj_body(const float* __restrict__ X,
    const float* __restrict__ bias, const unsigned short* __restrict__ wbase_g,
    unsigned short* __restrict__ outg, char* smem, int w0, int nwin)
{
  constexpr int NKS = KC / 32;
  constexpr int SH  = (KC == 128) ? 8 : 9;
  constexpr int WBYTES = KC * 128 * 2;
  const int tid = threadIdx.x;
  const int wave = tid >> 6, lane = tid & 63;
  const int g = lane >> 4, c16 = lane & 15;

  // stage weights once (linear LDS, pre-swizzled in ws)
#pragma unroll
  for (int i = 0; i < WBYTES/4096; ++i)
    gload_lds16(reinterpret_cast<const char*>(wbase_g) + i*4096 + tid*16, smem + i*4096 + tid*16);
  __syncthreads();
  char* outstage = smem + WBYTES;

  float bias_r[8];
#pragma unroll
  for (int ct = 0; ct < 8; ++ct) bias_r[ct] = bias[ct*16 + c16];

  const int rA = 16*wave + c16;
  const int rowoff = ((rA >> 3) << 8) + (rA & 7);   // token offset within image for this lane's row

  float4 raw[2*NKS];
  {
    const int win = w0;
    const long winbase = (long)(win >> 10)*65536 + (long)((win >> 5) & 31)*2048 + (win & 31)*8;
    const float* xrow = X + (winbase + rowoff) * KC;
#pragma unroll
    for (int ks = 0; ks < NKS; ++ks){
      const float4* p = reinterpret_cast<const float4*>(xrow + 32*ks + 8*g);
      raw[2*ks] = p[0]; raw[2*ks+1] = p[1];
    }
  }

  for (int wl = 0; wl < nwin; ++wl){
    const int win = w0 + wl;
    // convert current A (waits on this window's loads; prefetch from prev iter already landed)
    bf16x8 a[NKS];
#pragma unroll
    for (int ks = 0; ks < NKS; ++ks){
      const float4 x0 = raw[2*ks], x1 = raw[2*ks+1];
      bf16x8 t;
      t[0]=(short)f2bf(x0.x); t[1]=(short)f2bf(x0.y); t[2]=(short)f2bf(x0.z); t[3]=(short)f2bf(x0.w);
      t[4]=(short)f2bf(x1.x); t[5]=(short)f2bf(x1.y); t[6]=(short)f2bf(x1.z); t[7]=(short)f2bf(x1.w);
      a[ks] = t;
    }
    // prefetch next window's A (in flight across MFMA + writeout)
    if (wl + 1 < nwin){
      const int win2 = win + 1;
      const long wb2 = (long)(win2 >> 10)*65536 + (long)((win2 >> 5) & 31)*2048 + (win2 & 31)*8;
      const float* xrow2 = X + (wb2 + rowoff) * KC;
#pragma unroll
      for (int ks = 0; ks < NKS; ++ks){
        const float4* p = reinterpret_cast<const float4*>(xrow2 + 32*ks + 8*g);
        raw[2*ks] = p[0]; raw[2*ks+1] = p[1];
      }
    }
    // MFMA
    f32x4 acc[8];
#pragma unroll
    for (int ct = 0; ct < 8; ++ct) acc[ct] = f32x4{0.f,0.f,0.f,0.f};
#pragma unroll
    for (int ct = 0; ct < 8; ++ct){
      const int n = ct*16 + c16;
#pragma unroll
      for (int ks = 0; ks < NKS; ++ks){
        const bf16x8 b = *reinterpret_cast<const bf16x8*>(
            smem + ((n << SH) + (((32*ks + 8*g) << 1) ^ ((n & 7) << 4))));
        acc[ct] = mfma16(a[ks], b, acc[ct]);
      }
    }

    if (MODE == 0){
      // per-wave outstage region [wave*4096, +4096): no block barrier needed
#pragma unroll
      for (int ct = 0; ct < 8; ++ct){
#pragma unroll
        for (int r = 0; r < 4; ++r){
          const int row = 16*wave + 4*g + r;
          const int off = (row << 8) + (((ct*16 + c16) << 1) ^ ((row & 15) << 4));
          *reinterpret_cast<unsigned short*>(outstage + off) = f2bf(acc[ct][r] + bias_r[ct]);
        }
      }
      asm volatile("s_waitcnt lgkmcnt(0)" ::: "memory");
      char* dst = reinterpret_cast<char*>(outg) + (size_t)win * 16384 + wave*4096;
      const char* srcs = outstage + wave*4096;
#pragma unroll
      for (int i = 0; i < 4; ++i){
        const uint4 d = *reinterpret_cast<const uint4*>(srcs + i*1024 + lane*16);
        *reinterpret_cast<uint4*>(dst + i*1024 + lane*16) = d;
      }
    } else {
      // v: u16 scatter into block outstage in vt layout, then coalesced block copy
#pragma unroll
      for (int ct = 0; ct < 8; ++ct){
#pragma unroll
        for (int r = 0; r < 4; ++r){
          const int key = 16*wave + 4*g + r;
          const int off = (ct << 11) + (c16 << 7) + ((key << 1) ^ ((c16 & 7) << 4));
          *reinterpret_cast<unsigned short*>(outstage + off) = f2bf(acc[ct][r] + bias_r[ct]);
        }
      }
      __syncthreads();
      char* dst = reinterpret_cast<char*>(outg) + (size_t)win * 16384;
#pragma unroll
      for (int i = 0; i < 4; ++i){
        const uint4 d = *reinterpret_cast<const uint4*>(outstage + tid*16 + i*4096);
        *reinterpret_cast<uint4*>(dst + tid*16 + i*4096) = d;
      }
      __syncthreads();   // before next window's scatter overwrites outstage
    }
  }
}

__global__ __launch_bounds__(256, 3) void proj_q(const float* __restrict__ qq,
    const float* __restrict__ b_q, const unsigned short* __restrict__ wsu,
    unsigned short* __restrict__ qs)
{
  __shared__ char smem[49152];   // 32K weights + 16K outstage
  proj_body<128,0>(qq, b_q, wsu, qs, smem, blockIdx.x*8, 8);
}
__global__ __launch_bounds__(256, 3) void proj_v(const float* __restrict__ vv,
    const float* __restrict__ b_v, const unsigned short* __restrict__ wsu,
    unsigned short* __restrict__ vsg)
{
  __shared__ char smem[49152];   // 32K weights + 16K outstage
  proj_body<128,2>(vv, b_v, wsu + 16384, vsg, smem, blockIdx.x*8, 8);
}
__global__ __launch_bounds__(256, 2) void proj_k(const float* __restrict__ kkin,
    const float* __restrict__ b_k, const unsigned short* __restrict__ wsu,
    unsigned short* __restrict__ ksg)
{
  __shared__ char smem[81920];   // 64K weights + 16K outstage
  proj_body<256,0>(kkin, b_k, wsu + 32768, ksg, smem, blockIdx.x*8, 8);
}

// =================== attention + o-projection, 512 threads / window ===========
__global__ __launch_bounds__(512, 4) void attn_kernel(
    const unsigned short* __restrict__ qs, const unsigned short* __restrict__ ksg,
    const unsigned short* __restrict__ vsg, const unsigned short* __restrict__ wsu,
    const float* __restrict__ b_o, float* __restrict__ out)
{
  __shared__ char smem[49152];   // q 16K | k 16K | vt 16K ; after: yh [0,16K), yl [16K,32K)
  const int tid = threadIdx.x;
  const int wave = tid >> 6, lane = tid & 63;
  const int l31 = lane & 31, h5 = lane >> 5;
  const int qh = wave & 1, hp = wave >> 1;

  const int win = blockIdx.x;
  const int bb = win >> 10, wy = (win >> 5) & 31, wx = win & 31;
  const long winbase = (long)bb * 65536 + (long)wy * 2048 + wx * 8;

  const u32* bias_u = reinterpret_cast<const u32*>(wsu + 98304);

  {
    const char* srcs[3] = {
      reinterpret_cast<const char*>(qs)  + (size_t)win * 16384,
      reinterpret_cast<const char*>(ksg) + (size_t)win * 16384,
      reinterpret_cast<const char*>(vsg) + (size_t)win * 16384 };
#pragma unroll
    for (int rg = 0; rg < 3; ++rg)
#pragma unroll
      for (int j = 0; j < 2; ++j){
        const int off = j*8192 + tid*16;
        gload_lds16(srcs[rg] + off, smem + rg*16384 + off);
      }
  }
  __syncthreads();

  f32x16 y[2];
#pragma unroll
  for (int hh = 0; hh < 2; ++hh){
    const int h = 2*hp + hh;
    const int chb = (h*16 + 8*h5) * 2;
    bf16x8 kf0, kf1, qf;
    { const int row = l31;
      kf0 = *reinterpret_cast<const bf16x8*>(smem + KP_BASE + (row<<8) + (chb ^ ((row&15)<<4))); }
    { const int row = 32 + l31;
      kf1 = *reinterpret_cast<const bf16x8*>(smem + KP_BASE + (row<<8) + (chb ^ ((row&15)<<4))); }
    { const int row = qh*32 + l31;
      qf  = *reinterpret_cast<const bf16x8*>(smem + QP_BASE + (row<<8) + (chb ^ ((row&15)<<4))); }
    f32x16 z = {};
    f32x16 s0 = mfma32(kf0, qf, z);
    f32x16 s1 = mfma32(kf1, qf, z);

    const u32* bb2 = bias_u + ((((h*2 + qh)*2 + 0)*2 + h5)*8)*32 + l31;
    float t[32];
#pragma unroll
    for (int i = 0; i < 8; ++i){
      const u32 w0 = bb2[i*32];
      const u32 w1 = bb2[512 + i*32];
      t[2*i]     = fmaf(s0[2*i],   0.25f, bf2f((unsigned short)(w0 & 0xffff)));
      t[2*i+1]   = fmaf(s0[2*i+1], 0.25f, bf2f((unsigned short)(w0 >> 16)));
      t[16+2*i]  = fmaf(s1[2*i],   0.25f, bf2f((unsigned short)(w1 & 0xffff)));
      t[17+2*i]  = fmaf(s1[2*i+1], 0.25f, bf2f((unsigned short)(w1 >> 16)));
    }
    float m = t[0];
#pragma unroll
    for (int r = 1; r < 32; ++r) m = fmaxf(m, t[r]);
    m = fmaxf(m, __shfl_xor(m, 32));
    float sum = 0.f;
#pragma unroll
    for (int r = 0; r < 32; ++r){ t[r] = __expf(t[r] - m); sum += t[r]; }
    sum += __shfl_xor(sum, 32);
    const float rs = 1.0f / sum;
    u32 pk0[8], pk1[8];
#pragma unroll
    for (int i = 0; i < 8; ++i){
      pk0[i] = pack2bf(t[2*i]*rs,    t[2*i+1]*rs);
      pk1[i] = pack2bf(t[16+2*i]*rs, t[17+2*i]*rs);
    }

    f32x16 yy = {};
    const int chr = l31 & 15;
#pragma unroll
    for (int m4 = 0; m4 < 4; ++m4){
      const int jb = 4*(m4 & 1);
      const u32 a0 = (m4 < 2) ? pk0[jb]   : pk1[jb];
      const u32 a1 = (m4 < 2) ? pk0[jb+1] : pk1[jb+1];
      const u32 a2 = (m4 < 2) ? pk0[jb+2] : pk1[jb+2];
      const u32 a3 = (m4 < 2) ? pk0[jb+3] : pk1[jb+3];
      const u32 s0w = (u32)__shfl_xor((int)a0, 32);
      const u32 s1w = (u32)__shfl_xor((int)a1, 32);
      const u32 s2w = (u32)__shfl_xor((int)a2, 32);
      const u32 s3w = (u32)__shfl_xor((int)a3, 32);
      union { u32 w[4]; bf16x8 v; } afu;
      afu.w[0] = h5 ? s2w : a0;
      afu.w[1] = h5 ? s3w : a1;
      afu.w[2] = h5 ? a2  : s0w;
      afu.w[3] = h5 ? a3  : s1w;
      const int kb = 32*m4 + 16*h5;
      const bf16x8 bv = *reinterpret_cast<const bf16x8*>(
          smem + VT_BASE + (h<<11) + (chr<<7) + (kb ^ ((chr & 7) << 4)));
      yy = mfma32(afu.v, bv, yy);
    }
    y[hh] = yy;
  }
  __syncthreads();

  if (l31 < 16){
#pragma unroll
    for (int hh = 0; hh < 2; ++hh){
      const int ch = (2*hp + hh)*16 + l31;
#pragma unroll
      for (int r = 0; r < 16; ++r){
        const int row = qh*32 + (r & 3) + 8*(r >> 2) + 4*h5;
        const float v = y[hh][r];
        const unsigned short hv = f2bf(v);
        const unsigned short lv = f2bf(v - bf2f(hv));
        const int byte = (row << 8) + ((ch << 1) ^ ((row & 15) << 4));
        *reinterpret_cast<unsigned short*>(smem + byte)         = hv;
        *reinterpret_cast<unsigned short*>(smem + 16384 + byte) = lv;
      }
    }
  }
  __syncthreads();

  {
    const int g = lane >> 4, c16 = lane & 15;
    const int ct = wave;
    const unsigned short* WT_oh = wsu + 65536;
    const unsigned short* WT_ol = wsu + 81920;
    bf16x8 bh[4], bl[4];
#pragma unroll
    for (int ks = 0; ks < 4; ++ks){
      bh[ks] = *reinterpret_cast<const bf16x8*>(WT_oh + (ct*16+c16)*128 + 32*ks + 8*g);
      bl[ks] = *reinterpret_cast<const bf16x8*>(WT_ol + (ct*16+c16)*128 + 32*ks + 8*g);
    }
    const float bov = b_o[ct*16 + c16];
#pragma unroll
    for (int rt = 0; rt < 4; ++rt){
      const int row2 = rt*16 + c16;
      bf16x8 ah[4], al[4];
#pragma unroll
      for (int ks = 0; ks < 4; ++ks){
        const int byte = (row2 << 8) + ((64*ks + 16*g) ^ ((row2 & 15) << 4));
        ah[ks] = *reinterpret_cast<const bf16x8*>(smem + byte);
        al[ks] = *reinterpret_cast<const bf16x8*>(smem + 16384 + byte);
      }
      f32x4 acc = {};
#pragma unroll
      for (int ks = 0; ks < 4; ++ks){
        acc = mfma16(ah[ks], bh[ks], acc);
        acc = mfma16(al[ks], bh[ks], acc);
        acc = mfma16(ah[ks], bl[ks], acc);
      }
#pragma unroll
      for (int r = 0; r < 4; ++r){
        const int R = rt*16 + 4*g + r;
        const long tok = winbase + (long)(R >> 3)*256 + (R & 7);
        out[tok*128 + ct*16 + c16] = acc[r] + bov;
      }
    }
  }
}

extern "C" void kernel_launch(void* const* d_in, const int* in_sizes, int n_in,
                              void* d_out, int out_size, void* d_ws, size_t ws_size,
                              hipStream_t stream)
{
  (void)in_sizes; (void)n_in; (void)out_size; (void)ws_size;
  const float* qq   = (const float*)d_in[0];
  const float* kk   = (const float*)d_in[1];
  const float* vv   = (const float*)d_in[2];
  const float* w_q  = (const float*)d_in[3];
  const float* b_q  = (const float*)d_in[4];
  const float* w_k  = (const float*)d_in[5];
  const float* b_k  = (const float*)d_in[6];
  const float* w_v  = (const float*)d_in[7];
  const float* b_v  = (const float*)d_in[8];
  const float* w_o  = (const float*)d_in[9];
  const float* b_o  = (const float*)d_in[10];
  const float* btab = (const float*)d_in[11];
  unsigned short* wsu = (unsigned short*)d_ws;
  float* out = (float*)d_out;

  unsigned short* qsp = wsu + 131072;            // byte 262144
  unsigned short* ksp = qsp + 33554432;          // +64MB
  unsigned short* vsp = ksp + 33554432;          // +64MB

  prep_kernel<<<384, 256, 0, stream>>>(w_q, w_k, w_v, w_o, btab, wsu);
  proj_q<<<512, 256, 0, stream>>>(qq, b_q, wsu, qsp);
  proj_v<<<512, 256, 0, stream>>>(vv, b_v, wsu, vsp);
  proj_k<<<512, 256, 0, stream>>>(kk, b_k, wsu, ksp);
  attn_kernel<<<4096, 512, 0, stream>>>(qsp, ksp, vsp, wsu, b_o, out);
}

// Round 6
// 272.819 us; speedup vs baseline: 1.1390x; 1.0052x over previous
//
#include <hip/hip_runtime.h>
#include <cstdint>

typedef float f32x4  __attribute__((ext_vector_type(4)));
typedef float f32x16 __attribute__((ext_vector_type(16)));
typedef short bf16x8 __attribute__((ext_vector_type(8)));
typedef unsigned int u32;

#define QP_BASE 0
#define KP_BASE 16384
#define VT_BASE 32768

__device__ __forceinline__ unsigned short f2bf(float f){
  union { float f; uint32_t u; } v; v.f = f;
  uint32_t u = v.u;
  return (unsigned short)((u + 0x7FFFu + ((u >> 16) & 1u)) >> 16);  // RNE
}
__device__ __forceinline__ float bf2f(unsigned short h){
  union { uint32_t u; float f; } v; v.u = ((uint32_t)h) << 16;
  return v.f;
}
__device__ __forceinline__ u32 pack2bf(float a, float b){
  return (u32)f2bf(a) | ((u32)f2bf(b) << 16);
}
__device__ __forceinline__ f32x4 mfma16(bf16x8 a, bf16x8 b, f32x4 c){
  return __builtin_amdgcn_mfma_f32_16x16x32_bf16(a, b, c, 0, 0, 0);
}
__device__ __forceinline__ f32x16 mfma32(bf16x8 a, bf16x8 b, f32x16 c){
  return __builtin_amdgcn_mfma_f32_32x32x16_bf16(a, b, c, 0, 0, 0);
}
__device__ __forceinline__ void gload_lds16(const void* gsrc, void* ldst){
  __builtin_amdgcn_global_load_lds(
    (const __attribute__((address_space(1))) unsigned int*)gsrc,
    (__attribute__((address_space(3))) unsigned int*)ldst, 16, 0, 0);
}

// ---------------- prep ----------------
// wsu layout (shorts): WT_q [0,16384) | WT_v [16384,32768) | WT_k [32768,65536)
//   WT_oh [65536,81920) | WT_ol [81920,98304) | bias_t u32[16384] at short 98304
__global__ void prep_kernel(const float* __restrict__ wq, const float* __restrict__ wk,
                            const float* __restrict__ wv, const float* __restrict__ wo,
                            const float* __restrict__ btab, unsigned short* __restrict__ wsu)
{
  const int idx = blockIdx.x * 256 + threadIdx.x;
  if (idx < 16384){                          // WT_q[n][k] = wq[k][n], k-swizzled
    const int n = idx >> 7, k = idx & 127;
    wsu[n*128 + (k ^ ((n & 7) << 3))] = f2bf(wq[k*128 + n]);
  } else if (idx < 32768){                   // WT_v
    const int i = idx - 16384, n = i >> 7, k = i & 127;
    wsu[16384 + n*128 + (k ^ ((n & 7) << 3))] = f2bf(wv[k*128 + n]);
  } else if (idx < 65536){                   // WT_k (K=256)
    const int i = idx - 32768, n = i >> 8, k = i & 255;
    wsu[32768 + n*256 + (k ^ ((n & 7) << 3))] = f2bf(wk[k*128 + n]);
  } else if (idx < 81920){                   // WT_o hi/lo (linear [n][k])
    const int i = idx - 65536, n = i >> 7, k = i & 127;
    const float f = wo[k*128 + n];
    const unsigned short hv = f2bf(f);
    wsu[65536 + n*128 + k] = hv;
    wsu[81920 + n*128 + k] = f2bf(f - bf2f(hv));
  } else if (idx < 98304){                   // bias_t (reg-layout bf16 pairs)
    const int i = idx - 81920;
    const int q  = i & 31;
    const int ib = (i >> 5) & 7;
    const int h5 = (i >> 8) & 1;
    const int t  = (i >> 9) & 1;
    const int qh = (i >> 10) & 1;
    const int h  = (i >> 11);
    const int qg = qh*32 + q;
    const int qi = qg >> 3, qj = qg & 7;
    u32 wv2 = 0;
#pragma unroll
    for (int e = 0; e < 2; ++e){
      const int r = 2*ib + e;
      const int key = t*32 + 4*h5 + (r & 3) + 8*(r >> 2);
      const int ki = key >> 3, kj = key & 7;
      const int rel = (qi - ki + 7) * 15 + (qj - kj + 7);
      wv2 |= ((u32)f2bf(btab[rel*8 + h])) << (16*e);
    }
    reinterpret_cast<u32*>(wsu + 98304)[i] = wv2;
  }
}

// =================== merged projection kernel ===========
// MODE 0 (q/k): per-wave outstage -> coalesced copy. chunk byte = (row<<8) + ((ch*2)^((row&15)<<4))
// MODE 2 (v):  u16 scatter to block outstage in vt layout -> barrier -> coalesced copy.
//              vt byte = (ct<<11) + (c16<<7) + ((key*2)^((c16&7)<<4))
template<int KC, int MODE>
__device__ __forceinline__ void proj_body(const float* __restrict__ X,
    const float* __restrict__ bias, const unsigned short* __restrict__ wbase_g,
    unsigned short* __restrict__ outg, char* smem, int w0, int nwin)
{
  constexpr int NKS = KC / 32;
  constexpr int SH  = (KC == 128) ? 8 : 9;
  constexpr int WBYTES = KC * 128 * 2;
  const int tid = threadIdx.x;
  const int wave = tid >> 6, lane = tid & 63;
  const int g = lane >> 4, c16 = lane & 15;

  // stage weights once (linear LDS, pre-swizzled in ws)
#pragma unroll
  for (int i = 0; i < WBYTES/4096; ++i)
    gload_lds16(reinterpret_cast<const char*>(wbase_g) + i*4096 + tid*16, smem + i*4096 + tid*16);
  __syncthreads();
  char* outstage = smem + WBYTES;

  float bias_r[8];
#pragma unroll
  for (int ct = 0; ct < 8; ++ct) bias_r[ct] = bias[ct*16 + c16];

  const int rA = 16*wave + c16;
  const int rowoff = ((rA >> 3) << 8) + (rA & 7);   // token offset within image for this lane's row

  auto issue = [&](int win, float4 (&raw)[2*NKS]){
    const long wb = (long)(win >> 10)*65536 + (long)((win >> 5) & 31)*2048 + (win & 31)*8;
    const float* xrow = X + (wb + rowoff) * KC;
#pragma unroll
    for (int ks = 0; ks < NKS; ++ks){
      const float4* p = reinterpret_cast<const float4*>(xrow + 32*ks + 8*g);
      raw[2*ks] = p[0]; raw[2*ks+1] = p[1];
    }
  };

  auto step = [&](int wl, float4 (&raw)[2*NKS]){
    const int win = w0 + wl;
    // convert this window's A (compiler waits only on this buffer's loads)
    bf16x8 a[NKS];
#pragma unroll
    for (int ks = 0; ks < NKS; ++ks){
      const float4 x0 = raw[2*ks], x1 = raw[2*ks+1];
      bf16x8 t;
      t[0]=(short)f2bf(x0.x); t[1]=(short)f2bf(x0.y); t[2]=(short)f2bf(x0.z); t[3]=(short)f2bf(x0.w);
      t[4]=(short)f2bf(x1.x); t[5]=(short)f2bf(x1.y); t[6]=(short)f2bf(x1.z); t[7]=(short)f2bf(x1.w);
      a[ks] = t;
    }
    // 2-deep prefetch: reuse the buffer just freed
    if (wl + 2 < nwin) issue(win + 2, raw);
    // MFMA
    f32x4 acc[8];
#pragma unroll
    for (int ct = 0; ct < 8; ++ct) acc[ct] = f32x4{0.f,0.f,0.f,0.f};
#pragma unroll
    for (int ct = 0; ct < 8; ++ct){
      const int n = ct*16 + c16;
#pragma unroll
      for (int ks = 0; ks < NKS; ++ks){
        const bf16x8 b = *reinterpret_cast<const bf16x8*>(
            smem + ((n << SH) + (((32*ks + 8*g) << 1) ^ ((n & 7) << 4))));
        acc[ct] = mfma16(a[ks], b, acc[ct]);
      }
    }

    if (MODE == 0){
      // per-wave outstage region [wave*4096, +4096): no block barrier needed
#pragma unroll
      for (int ct = 0; ct < 8; ++ct){
#pragma unroll
        for (int r = 0; r < 4; ++r){
          const int row = 16*wave + 4*g + r;
          const int off = (row << 8) + (((ct*16 + c16) << 1) ^ ((row & 15) << 4));
          *reinterpret_cast<unsigned short*>(outstage + off) = f2bf(acc[ct][r] + bias_r[ct]);
        }
      }
      asm volatile("s_waitcnt lgkmcnt(0)" ::: "memory");
      char* dst = reinterpret_cast<char*>(outg) + (size_t)win * 16384 + wave*4096;
      const char* srcs = outstage + wave*4096;
#pragma unroll
      for (int i = 0; i < 4; ++i){
        const uint4 d = *reinterpret_cast<const uint4*>(srcs + i*1024 + lane*16);
        *reinterpret_cast<uint4*>(dst + i*1024 + lane*16) = d;
      }
    } else {
      // v: u16 scatter into block outstage in vt layout, then coalesced block copy
#pragma unroll
      for (int ct = 0; ct < 8; ++ct){
#pragma unroll
        for (int r = 0; r < 4; ++r){
          const int key = 16*wave + 4*g + r;
          const int off = (ct << 11) + (c16 << 7) + ((key << 1) ^ ((c16 & 7) << 4));
          *reinterpret_cast<unsigned short*>(outstage + off) = f2bf(acc[ct][r] + bias_r[ct]);
        }
      }
      __syncthreads();
      char* dst = reinterpret_cast<char*>(outg) + (size_t)win * 16384;
#pragma unroll
      for (int i = 0; i < 4; ++i){
        const uint4 d = *reinterpret_cast<const uint4*>(outstage + tid*16 + i*4096);
        *reinterpret_cast<uint4*>(dst + tid*16 + i*4096) = d;
      }
      __syncthreads();   // before next window's scatter overwrites outstage
    }
  };

  float4 rawA[2*NKS], rawB[2*NKS];
  issue(w0, rawA);
  issue(w0 + 1, rawB);
  for (int wl = 0; wl < nwin; wl += 2){
    step(wl, rawA);
    step(wl + 1, rawB);
  }
}

__global__ __launch_bounds__(256, 2) void proj_all(
    const float* __restrict__ qq, const float* __restrict__ kkin, const float* __restrict__ vvin,
    const float* __restrict__ b_q, const float* __restrict__ b_k, const float* __restrict__ b_v,
    const unsigned short* __restrict__ wsu,
    unsigned short* __restrict__ qs, unsigned short* __restrict__ ksg, unsigned short* __restrict__ vsg)
{
  __shared__ char smem[81920];     // k path: 64K weights + 16K outstage; q/v use less
  const int type = blockIdx.x % 3;
  const int w0 = (blockIdx.x / 3) * 8;
  if (type == 0)      proj_body<128,0>(qq,   b_q, wsu,         qs,  smem, w0, 8);
  else if (type == 1) proj_body<128,2>(vvin, b_v, wsu + 16384, vsg, smem, w0, 8);
  else                proj_body<256,0>(kkin, b_k, wsu + 32768, ksg, smem, w0, 8);
}

// =================== attention + o-projection, 512 threads / window ===========
__global__ __launch_bounds__(512, 4) void attn_kernel(
    const unsigned short* __restrict__ qs, const unsigned short* __restrict__ ksg,
    const unsigned short* __restrict__ vsg, const unsigned short* __restrict__ wsu,
    const float* __restrict__ b_o, float* __restrict__ out)
{
  __shared__ char smem[49152];   // q 16K | k 16K | vt 16K ; after: yh [0,16K), yl [16K,32K)
  const int tid = threadIdx.x;
  const int wave = tid >> 6, lane = tid & 63;
  const int l31 = lane & 31, h5 = lane >> 5;
  const int qh = wave & 1, hp = wave >> 1;

  const int win = blockIdx.x;
  const int bb = win >> 10, wy = (win >> 5) & 31, wx = win & 31;
  const long winbase = (long)bb * 65536 + (long)wy * 2048 + wx * 8;

  const u32* bias_u = reinterpret_cast<const u32*>(wsu + 98304);

  {
    const char* srcs[3] = {
      reinterpret_cast<const char*>(qs)  + (size_t)win * 16384,
      reinterpret_cast<const char*>(ksg) + (size_t)win * 16384,
      reinterpret_cast<const char*>(vsg) + (size_t)win * 16384 };
#pragma unroll
    for (int rg = 0; rg < 3; ++rg)
#pragma unroll
      for (int j = 0; j < 2; ++j){
        const int off = j*8192 + tid*16;
        gload_lds16(srcs[rg] + off, smem + rg*16384 + off);
      }
  }
  __syncthreads();

  f32x16 y[2];
#pragma unroll
  for (int hh = 0; hh < 2; ++hh){
    const int h = 2*hp + hh;
    const int chb = (h*16 + 8*h5) * 2;
    bf16x8 kf0, kf1, qf;
    { const int row = l31;
      kf0 = *reinterpret_cast<const bf16x8*>(smem + KP_BASE + (row<<8) + (chb ^ ((row&15)<<4))); }
    { const int row = 32 + l31;
      kf1 = *reinterpret_cast<const bf16x8*>(smem + KP_BASE + (row<<8) + (chb ^ ((row&15)<<4))); }
    { const int row = qh*32 + l31;
      qf  = *reinterpret_cast<const bf16x8*>(smem + QP_BASE + (row<<8) + (chb ^ ((row&15)<<4))); }
    f32x16 z = {};
    f32x16 s0 = mfma32(kf0, qf, z);
    f32x16 s1 = mfma32(kf1, qf, z);

    const u32* bb2 = bias_u + ((((h*2 + qh)*2 + 0)*2 + h5)*8)*32 + l31;
    float t[32];
#pragma unroll
    for (int i = 0; i < 8; ++i){
      const u32 w0 = bb2[i*32];
      const u32 w1 = bb2[512 + i*32];
      t[2*i]     = fmaf(s0[2*i],   0.25f, bf2f((unsigned short)(w0 & 0xffff)));
      t[2*i+1]   = fmaf(s0[2*i+1], 0.25f, bf2f((unsigned short)(w0 >> 16)));
      t[16+2*i]  = fmaf(s1[2*i],   0.25f, bf2f((unsigned short)(w1 & 0xffff)));
      t[17+2*i]  = fmaf(s1[2*i+1], 0.25f, bf2f((unsigned short)(w1 >> 16)));
    }
    float m = t[0];
#pragma unroll
    for (int r = 1; r < 32; ++r) m = fmaxf(m, t[r]);
    m = fmaxf(m, __shfl_xor(m, 32));
    float sum = 0.f;
#pragma unroll
    for (int r = 0; r < 32; ++r){ t[r] = __expf(t[r] - m); sum += t[r]; }
    sum += __shfl_xor(sum, 32);
    const float rs = 1.0f / sum;
    u32 pk0[8], pk1[8];
#pragma unroll
    for (int i = 0; i < 8; ++i){
      pk0[i] = pack2bf(t[2*i]*rs,    t[2*i+1]*rs);
      pk1[i] = pack2bf(t[16+2*i]*rs, t[17+2*i]*rs);
    }

    f32x16 yy = {};
    const int chr = l31 & 15;
#pragma unroll
    for (int m4 = 0; m4 < 4; ++m4){
      const int jb = 4*(m4 & 1);
      const u32 a0 = (m4 < 2) ? pk0[jb]   : pk1[jb];
      const u32 a1 = (m4 < 2) ? pk0[jb+1] : pk1[jb+1];
      const u32 a2 = (m4 < 2) ? pk0[jb+2] : pk1[jb+2];
      const u32 a3 = (m4 < 2) ? pk0[jb+3] : pk1[jb+3];
      const u32 s0w = (u32)__shfl_xor((int)a0, 32);
      const u32 s1w = (u32)__shfl_xor((int)a1, 32);
      const u32 s2w = (u32)__shfl_xor((int)a2, 32);
      const u32 s3w = (u32)__shfl_xor((int)a3, 32);
      union { u32 w[4]; bf16x8 v; } afu;
      afu.w[0] = h5 ? s2w : a0;
      afu.w[1] = h5 ? s3w : a1;
      afu.w[2] = h5 ? a2  : s0w;
      afu.w[3] = h5 ? a3  : s1w;
      const int kb = 32*m4 + 16*h5;
      const bf16x8 bv = *reinterpret_cast<const bf16x8*>(
          smem + VT_BASE + (h<<11) + (chr<<7) + (kb ^ ((chr & 7) << 4)));
      yy = mfma32(afu.v, bv, yy);
    }
    y[hh] = yy;
  }
  __syncthreads();

  if (l31 < 16){
#pragma unroll
    for (int hh = 0; hh < 2; ++hh){
      const int ch = (2*hp + hh)*16 + l31;
#pragma unroll
      for (int r = 0; r < 16; ++r){
        const int row = qh*32 + (r & 3) + 8*(r >> 2) + 4*h5;
        const float v = y[hh][r];
        const unsigned short hv = f2bf(v);
        const unsigned short lv = f2bf(v - bf2f(hv));
        const int byte = (row << 8) + ((ch << 1) ^ ((row & 15) << 4));
        *reinterpret_cast<unsigned short*>(smem + byte)         = hv;
        *reinterpret_cast<unsigned short*>(smem + 16384 + byte) = lv;
      }
    }
  }
  __syncthreads();

  {
    const int g = lane >> 4, c16 = lane & 15;
    const int ct = wave;
    const unsigned short* WT_oh = wsu + 65536;
    const unsigned short* WT_ol = wsu + 81920;
    bf16x8 bh[4], bl[4];
#pragma unroll
    for (int ks = 0; ks < 4; ++ks){
      bh[ks] = *reinterpret_cast<const bf16x8*>(WT_oh + (ct*16+c16)*128 + 32*ks + 8*g);
      bl[ks] = *reinterpret_cast<const bf16x8*>(WT_ol + (ct*16+c16)*128 + 32*ks + 8*g);
    }
    const float bov = b_o[ct*16 + c16];
#pragma unroll
    for (int rt = 0; rt < 4; ++rt){
      const int row2 = rt*16 + c16;
      bf16x8 ah[4], al[4];
#pragma unroll
      for (int ks = 0; ks < 4; ++ks){
        const int byte = (row2 << 8) + ((64*ks + 16*g) ^ ((row2 & 15) << 4));
        ah[ks] = *reinterpret_cast<const bf16x8*>(smem + byte);
        al[ks] = *reinterpret_cast<const bf16x8*>(smem + 16384 + byte);
      }
      f32x4 acc = {};
#pragma unroll
      for (int ks = 0; ks < 4; ++ks){
        acc = mfma16(ah[ks], bh[ks], acc);
        acc = mfma16(al[ks], bh[ks], acc);
        acc = mfma16(ah[ks], bl[ks], acc);
      }
#pragma unroll
      for (int r = 0; r < 4; ++r){
        const int R = rt*16 + 4*g + r;
        const long tok = winbase + (long)(R >> 3)*256 + (R & 7);
        out[tok*128 + ct*16 + c16] = acc[r] + bov;
      }
    }
  }
}

extern "C" void kernel_launch(void* const* d_in, const int* in_sizes, int n_in,
                              void* d_out, int out_size, void* d_ws, size_t ws_size,
                              hipStream_t stream)
{
  (void)in_sizes; (void)n_in; (void)out_size; (void)ws_size;
  const float* qq   = (const float*)d_in[0];
  const float* kk   = (const float*)d_in[1];
  const float* vv   = (const float*)d_in[2];
  const float* w_q  = (const float*)d_in[3];
  const float* b_q  = (const float*)d_in[4];
  const float* w_k  = (const float*)d_in[5];
  const float* b_k  = (const float*)d_in[6];
  const float* w_v  = (const float*)d_in[7];
  const float* b_v  = (const float*)d_in[8];
  const float* w_o  = (const float*)d_in[9];
  const float* b_o  = (const float*)d_in[10];
  const float* btab = (const float*)d_in[11];
  unsigned short* wsu = (unsigned short*)d_ws;
  float* out = (float*)d_out;

  unsigned short* qsp = wsu + 131072;            // byte 262144
  unsigned short* ksp = qsp + 33554432;          // +64MB
  unsigned short* vsp = ksp + 33554432;          // +64MB

  prep_kernel<<<384, 256, 0, stream>>>(w_q, w_k, w_v, w_o, btab, wsu);
  proj_all<<<1536, 256, 0, stream>>>(qq, kk, vv, b_q, b_k, b_v, wsu, qsp, ksp, vsp);
  attn_kernel<<<4096, 512, 0, stream>>>(qsp, ksp, vsp, wsu, b_o, out);
}